// Round 6
// baseline (495.300 us; speedup 1.0000x reference)
//
#include <hip/hip_runtime.h>

#define N_NODES 100000
#define N_EDGES 600000
#define NT1 782    // node tiles of 128
#define NT2 4688   // edge tiles of 128
#define LDH 136    // padded row stride (f16 elems), 16B-aligned rows, 2-way-conflict free
#define G1H 512    // k1 blocks per half (grid = 1024)

typedef _Float16 f16x8 __attribute__((ext_vector_type(8)));
typedef __attribute__((ext_vector_type(4))) float f32x4;

__device__ __forceinline__ float elu_f(float v) {
    return v > 0.0f ? v : (__expf(v) - 1.0f);
}

// P[n][half*128 + j] = f16( x[n] @ W1[half*128 + k][j] ).  Single-pass f16 MFMA.
extern "C" __global__ __launch_bounds__(256, 4)
void k1_node_linear(const float* __restrict__ x, const float* __restrict__ W1,
                    _Float16* __restrict__ P) {
    __shared__ __align__(16) _Float16 sX[128 * LDH];

    const int t = threadIdx.x;
    const int w = t >> 6, lane = t & 63;
    const int ln = lane & 15, kg = lane >> 4;
    const int kcf = t & 15;
    const int lef = t >> 4;
    const int half = (blockIdx.x >= G1H) ? 1 : 0;
    const int t0 = blockIdx.x - half * G1H;

    f16x8 bf[2][4];
#pragma unroll
    for (int c = 0; c < 2; ++c) {
        const int n = w * 32 + c * 16 + ln;
#pragma unroll
        for (int ks = 0; ks < 4; ++ks) {
            f16x8 v;
#pragma unroll
            for (int j = 0; j < 8; ++j) {
                int k = half * 128 + ks * 32 + kg * 8 + j;
                v[j] = (_Float16)W1[k * 128 + n];
            }
            bf[c][ks] = v;
        }
    }

    for (int tile = t0; tile < NT1; tile += G1H) {
        const int n0 = tile * 128;
        __syncthreads();
#pragma unroll 2
        for (int r = 0; r < 8; ++r) {
            int le = r * 16 + lef;
            int n = n0 + le;
            float4 a0 = make_float4(0.f, 0.f, 0.f, 0.f), a1 = a0;
            if (n < N_NODES) {
                const float* p = x + (size_t)n * 128 + kcf * 8;
                a0 = *(const float4*)p; a1 = *(const float4*)(p + 4);
            }
            float f[8] = {a0.x, a0.y, a0.z, a0.w, a1.x, a1.y, a1.z, a1.w};
            f16x8 vh;
#pragma unroll
            for (int j = 0; j < 8; ++j) vh[j] = (_Float16)f[j];
            *(f16x8*)(&sX[le * LDH + kcf * 8]) = vh;
        }
        __syncthreads();

        f32x4 acc[8][2];
#pragma unroll
        for (int rt = 0; rt < 8; ++rt)
#pragma unroll
            for (int c = 0; c < 2; ++c) acc[rt][c] = (f32x4){0.f, 0.f, 0.f, 0.f};

#pragma unroll
        for (int ks = 0; ks < 4; ++ks) {
#pragma unroll
            for (int rt = 0; rt < 8; ++rt) {
                f16x8 a = *(const f16x8*)(&sX[(rt * 16 + ln) * LDH + ks * 32 + kg * 8]);
#pragma unroll
                for (int c = 0; c < 2; ++c)
                    acc[rt][c] = __builtin_amdgcn_mfma_f32_16x16x32_f16(a, bf[c][ks], acc[rt][c], 0, 0, 0);
            }
        }

        __syncthreads();
        // C-layout: col=lane&15, row=(lane>>4)*4+reg  [measured m89/m91]
#pragma unroll
        for (int rt = 0; rt < 8; ++rt)
#pragma unroll
            for (int c = 0; c < 2; ++c) {
                int col = w * 32 + c * 16 + ln;
#pragma unroll
                for (int reg = 0; reg < 4; ++reg) {
                    int row = rt * 16 + kg * 4 + reg;
                    sX[row * LDH + col] = (_Float16)acc[rt][c][reg];
                }
            }
        __syncthreads();
        {
            int row_l = t >> 1, seg = t & 1;
            int n = n0 + row_l;
            if (n < N_NODES) {
                _Float16* dst = P + (size_t)n * 256 + half * 128 + seg * 64;
                const _Float16* srcp = &sX[row_l * LDH + seg * 64];
#pragma unroll
                for (int i = 0; i < 8; ++i)
                    *(f16x8*)(dst + i * 8) = *(const f16x8*)(srcp + i * 8);
            }
        }
    }
}

// Per 128-edge tile: h1=elu(A[src]+B[tgt]+b1); h2=elu(h1@W2+b2); out=h2@W3+b3.
// Software-pipelined gather: tile t+1's 16 loads held in regs across tile t's compute.
extern "C" __global__ __launch_bounds__(256, 3)
void k2_edge_mlp(const _Float16* __restrict__ P, const void* __restrict__ eiv,
                 const float* __restrict__ b1, const float* __restrict__ W2,
                 const float* __restrict__ b2, const float* __restrict__ W3,
                 const float* __restrict__ b3, float* __restrict__ out) {
    __shared__ __align__(16) _Float16 sH[128 * LDH];
    __shared__ float sPart[4 * 128];
    __shared__ int sSrc[2][128], sTgt[2][128];
    __shared__ int sFlag;

    const int t = threadIdx.x;
    const int w = t >> 6, lane = t & 63;
    const int ln = lane & 15, kg = lane >> 4;
    const int kcf = t & 15;
    const int lef = t >> 4;
    const float b3v = b3[0];

    // int64-vs-int32 edge_index detection (wave 0, block-local).
    if (t < 64) {
        unsigned v = ((const unsigned*)eiv)[2 * t + 1];
        unsigned long long bm = __ballot(v == 0u);
        if (t == 0) sFlag = (bm == ~0ull) ? 1 : 0;
    }

    // Loop-invariant register caches.
    float b1v[8];
#pragma unroll
    for (int j = 0; j < 8; ++j) b1v[j] = b1[kcf * 8 + j];
    float w3v[2], b2v[2];
#pragma unroll
    for (int c = 0; c < 2; ++c) {
        int col = w * 32 + c * 16 + ln;
        w3v[c] = W3[col]; b2v[c] = b2[col];
    }

    // W2 fragments (single f16) for this wave's 32-col strip.
    f16x8 bf[2][4];
#pragma unroll
    for (int c = 0; c < 2; ++c) {
        const int n = w * 32 + c * 16 + ln;
#pragma unroll
        for (int ks = 0; ks < 4; ++ks) {
            f16x8 v;
#pragma unroll
            for (int j = 0; j < 8; ++j) {
                int k = ks * 32 + kg * 8 + j;
                v[j] = (_Float16)W2[k * 128 + n];
            }
            bf[c][ks] = v;
        }
    }
    __syncthreads();   // sFlag ready
    const int mode64 = sFlag;

    // Prologue: indices + gather issue for the first tile.
    int tile = blockIdx.x;
    int par = 0;
    if (t < 128 && tile < NT2) {
        int e = tile * 128 + t;
        int s = 0, g = 0;
        if (e < N_EDGES) {
            if (mode64) {
                s = (int)((const long long*)eiv)[e];
                g = (int)((const long long*)eiv)[N_EDGES + e];
            } else {
                s = ((const int*)eiv)[e];
                g = ((const int*)eiv)[N_EDGES + e];
            }
        }
        sSrc[0][t] = s; sTgt[0][t] = g;
    }
    __syncthreads();

    f16x8 Ga[8], Gb[8];
    if (tile < NT2) {
#pragma unroll
        for (int r = 0; r < 8; ++r) {
            int le = r * 16 + lef;
            int s = sSrc[0][le], g = sTgt[0][le];
            Ga[r] = *(const f16x8*)(P + (size_t)s * 256 + kcf * 8);
            Gb[r] = *(const f16x8*)(P + (size_t)g * 256 + 128 + kcf * 8);
        }
    }

    for (; tile < NT2; tile += gridDim.x) {
        const int e0 = tile * 128;

        // Stage h1 from the in-flight gather registers.
#pragma unroll 2
        for (int r = 0; r < 8; ++r) {
            int le = r * 16 + lef;
            f16x8 vh;
#pragma unroll
            for (int j = 0; j < 8; ++j) {
                float hv = elu_f((float)Ga[r][j] + (float)Gb[r][j] + b1v[j]);
                vh[j] = (_Float16)hv;
            }
            *(f16x8*)(&sH[le * LDH + kcf * 8]) = vh;
        }

        // Prefetch next tile's indices into the alternate buffer.
        const int nt = tile + gridDim.x;
        if (t < 128 && nt < NT2) {
            int e = nt * 128 + t;
            int s = 0, g = 0;
            if (e < N_EDGES) {
                if (mode64) {
                    s = (int)((const long long*)eiv)[e];
                    g = (int)((const long long*)eiv)[N_EDGES + e];
                } else {
                    s = ((const int*)eiv)[e];
                    g = ((const int*)eiv)[N_EDGES + e];
                }
            }
            sSrc[par ^ 1][t] = s; sTgt[par ^ 1][t] = g;
        }
        __syncthreads();   // A: sH ready + next idx ready

        // Issue next tile's gathers; latency hidden behind MFMA/layer3/out below.
        if (nt < NT2) {
#pragma unroll
            for (int r = 0; r < 8; ++r) {
                int le = r * 16 + lef;
                int s = sSrc[par ^ 1][le], g = sTgt[par ^ 1][le];
                Ga[r] = *(const f16x8*)(P + (size_t)s * 256 + kcf * 8);
                Gb[r] = *(const f16x8*)(P + (size_t)g * 256 + 128 + kcf * 8);
            }
        }

        // MFMA + fused layer 3, two row-halves (acc = 32 regs live).
#pragma unroll
        for (int rh = 0; rh < 2; ++rh) {
            f32x4 acc[4][2];
#pragma unroll
            for (int rt = 0; rt < 4; ++rt)
#pragma unroll
                for (int c = 0; c < 2; ++c) acc[rt][c] = (f32x4){0.f, 0.f, 0.f, 0.f};

#pragma unroll
            for (int ks = 0; ks < 4; ++ks) {
#pragma unroll
                for (int rt = 0; rt < 4; ++rt) {
                    int row = (rh * 4 + rt) * 16 + ln;
                    f16x8 a = *(const f16x8*)(&sH[row * LDH + ks * 32 + kg * 8]);
#pragma unroll
                    for (int c = 0; c < 2; ++c)
                        acc[rt][c] = __builtin_amdgcn_mfma_f32_16x16x32_f16(a, bf[c][ks], acc[rt][c], 0, 0, 0);
                }
            }

#pragma unroll
            for (int rt = 0; rt < 4; ++rt) {
                float p[4] = {0.f, 0.f, 0.f, 0.f};
#pragma unroll
                for (int c = 0; c < 2; ++c) {
#pragma unroll
                    for (int reg = 0; reg < 4; ++reg)
                        p[reg] += elu_f(acc[rt][c][reg] + b2v[c]) * w3v[c];
                }
#pragma unroll
                for (int m = 1; m < 16; m <<= 1)
#pragma unroll
                    for (int reg = 0; reg < 4; ++reg) p[reg] += __shfl_xor(p[reg], m, 64);
                if (ln == 0) {
#pragma unroll
                    for (int reg = 0; reg < 4; ++reg)
                        sPart[w * 128 + (rh * 4 + rt) * 16 + kg * 4 + reg] = p[reg];
                }
            }
        }
        __syncthreads();   // B: sPart ready; all sH reads done

        if (t < 128) {
            int e = e0 + t;
            if (e < N_EDGES)
                out[e] = sPart[t] + sPart[128 + t] + sPart[256 + t] + sPart[384 + t] + b3v;
        }
        __syncthreads();   // C: sPart consumed; sH free for next stage
        par ^= 1;
    }
}

extern "C" void kernel_launch(void* const* d_in, const int* in_sizes, int n_in,
                              void* d_out, int out_size, void* d_ws, size_t ws_size,
                              hipStream_t stream) {
    const float* x  = (const float*)d_in[0];
    const void*  ei = d_in[1];
    const float* W1 = (const float*)d_in[2];
    const float* b1 = (const float*)d_in[3];
    const float* W2 = (const float*)d_in[4];
    const float* b2 = (const float*)d_in[5];
    const float* W3 = (const float*)d_in[6];
    const float* b3 = (const float*)d_in[7];
    float* out = (float*)d_out;

    _Float16* P = (_Float16*)((char*)d_ws + 256);  // 100000*256 f16 = 51.2 MB

    k1_node_linear<<<1024, 256, 0, stream>>>(x, W1, P);
    k2_edge_mlp<<<1024, 256, 0, stream>>>(P, ei, b1, W2, b2, W3, b3, out);
}

// Round 7
// 328.346 us; speedup vs baseline: 1.5085x; 1.5085x over previous
//
#include <hip/hip_runtime.h>

#define N_NODES 100000
#define N_EDGES 600000
#define NT1 782    // node tiles of 128
#define NT2 4688   // edge tiles of 128
#define LDH 136    // padded row stride (f16 elems), 16B-aligned rows, 2-way-conflict free
#define G1H 512    // k1 blocks per half (grid = 1024)

typedef _Float16 f16x8 __attribute__((ext_vector_type(8)));
typedef __attribute__((ext_vector_type(4))) float f32x4;

__device__ __forceinline__ float elu_f(float v) {
    return v > 0.0f ? v : (__expf(v) - 1.0f);
}

// P[n][half*128 + j] = f16( x[n] @ W1[half*128 + k][j] ).  Single-pass f16 MFMA.
extern "C" __global__ __launch_bounds__(256, 4)
void k1_node_linear(const float* __restrict__ x, const float* __restrict__ W1,
                    _Float16* __restrict__ P) {
    __shared__ __align__(16) _Float16 sX[128 * LDH];

    const int t = threadIdx.x;
    const int w = t >> 6, lane = t & 63;
    const int ln = lane & 15, kg = lane >> 4;
    const int kcf = t & 15;
    const int lef = t >> 4;
    const int half = (blockIdx.x >= G1H) ? 1 : 0;
    const int t0 = blockIdx.x - half * G1H;

    f16x8 bf[2][4];
#pragma unroll
    for (int c = 0; c < 2; ++c) {
        const int n = w * 32 + c * 16 + ln;
#pragma unroll
        for (int ks = 0; ks < 4; ++ks) {
            f16x8 v;
#pragma unroll
            for (int j = 0; j < 8; ++j) {
                int k = half * 128 + ks * 32 + kg * 8 + j;
                v[j] = (_Float16)W1[k * 128 + n];
            }
            bf[c][ks] = v;
        }
    }

    for (int tile = t0; tile < NT1; tile += G1H) {
        const int n0 = tile * 128;
        __syncthreads();
#pragma unroll 2
        for (int r = 0; r < 8; ++r) {
            int le = r * 16 + lef;
            int n = n0 + le;
            float4 a0 = make_float4(0.f, 0.f, 0.f, 0.f), a1 = a0;
            if (n < N_NODES) {
                const float* p = x + (size_t)n * 128 + kcf * 8;
                a0 = *(const float4*)p; a1 = *(const float4*)(p + 4);
            }
            float f[8] = {a0.x, a0.y, a0.z, a0.w, a1.x, a1.y, a1.z, a1.w};
            f16x8 vh;
#pragma unroll
            for (int j = 0; j < 8; ++j) vh[j] = (_Float16)f[j];
            *(f16x8*)(&sX[le * LDH + kcf * 8]) = vh;
        }
        __syncthreads();

        f32x4 acc[8][2];
#pragma unroll
        for (int rt = 0; rt < 8; ++rt)
#pragma unroll
            for (int c = 0; c < 2; ++c) acc[rt][c] = (f32x4){0.f, 0.f, 0.f, 0.f};

#pragma unroll
        for (int ks = 0; ks < 4; ++ks) {
#pragma unroll
            for (int rt = 0; rt < 8; ++rt) {
                f16x8 a = *(const f16x8*)(&sX[(rt * 16 + ln) * LDH + ks * 32 + kg * 8]);
#pragma unroll
                for (int c = 0; c < 2; ++c)
                    acc[rt][c] = __builtin_amdgcn_mfma_f32_16x16x32_f16(a, bf[c][ks], acc[rt][c], 0, 0, 0);
            }
        }

        __syncthreads();
        // C-layout: col=lane&15, row=(lane>>4)*4+reg  [measured m89/m91]
#pragma unroll
        for (int rt = 0; rt < 8; ++rt)
#pragma unroll
            for (int c = 0; c < 2; ++c) {
                int col = w * 32 + c * 16 + ln;
#pragma unroll
                for (int reg = 0; reg < 4; ++reg) {
                    int row = rt * 16 + kg * 4 + reg;
                    sX[row * LDH + col] = (_Float16)acc[rt][c][reg];
                }
            }
        __syncthreads();
        {
            int row_l = t >> 1, seg = t & 1;
            int n = n0 + row_l;
            if (n < N_NODES) {
                _Float16* dst = P + (size_t)n * 256 + half * 128 + seg * 64;
                const _Float16* srcp = &sX[row_l * LDH + seg * 64];
#pragma unroll
                for (int i = 0; i < 8; ++i)
                    *(f16x8*)(dst + i * 8) = *(const f16x8*)(srcp + i * 8);
            }
        }
    }
}

// Barrier-free k2: lane<->edge, quad<->k-chunk, so the gather IS the MFMA A-fragment.
// Each wave owns 32 edges x 128 cols; W2^T in LDS (read-only after init); layer-3 fused
// with an ln-only shuffle reduce; direct global out-writes. No __syncthreads in the loop.
extern "C" __global__ __launch_bounds__(256, 3)
void k2_edge_mlp(const _Float16* __restrict__ P, const void* __restrict__ eiv,
                 const float* __restrict__ b1, const float* __restrict__ W2,
                 const float* __restrict__ b2, const float* __restrict__ W3,
                 const float* __restrict__ b3, float* __restrict__ out) {
    __shared__ __align__(16) _Float16 sW2T[128 * LDH];   // [n][k] padded
    __shared__ int sFlag;

    const int t = threadIdx.x;
    const int w = t >> 6, lane = t & 63;
    const int ln = lane & 15, kg = lane >> 4;
    const float b3v = b3[0];

    // int64-vs-int32 edge_index detection (wave 0).
    if (t < 64) {
        unsigned v = ((const unsigned*)eiv)[2 * t + 1];
        unsigned long long bm = __ballot(v == 0u);
        if (t == 0) sFlag = (bm == ~0ull) ? 1 : 0;
    }

    // Stage W2^T into LDS: sW2T[n][k] = W2[k][n] (coalesced global reads).
#pragma unroll 4
    for (int r = 0; r < 64; ++r) {
        int idx = r * 256 + t;          // 16384 elems
        int k = idx >> 7, n = idx & 127;
        sW2T[n * LDH + k] = (_Float16)W2[k * 128 + n];
    }

    // Per-lane loop invariants.
    f16x8 b1f[4];
#pragma unroll
    for (int ks = 0; ks < 4; ++ks)
#pragma unroll
        for (int j = 0; j < 8; ++j) b1f[ks][j] = (_Float16)b1[ks * 32 + kg * 8 + j];
    float w3v[8], b2v[8];
#pragma unroll
    for (int cg = 0; cg < 8; ++cg) {
        int col = cg * 16 + ln;
        w3v[cg] = W3[col]; b2v[cg] = b2[col];
    }
    __syncthreads();   // sW2T + sFlag ready; ONLY barrier in the kernel
    const int mode64 = sFlag;

    for (int tile = blockIdx.x; tile < NT2; tile += gridDim.x) {
        const int ebase = tile * 128 + w * 32;

        // Edge indices for this wave's 2 row-groups (redundant across kg quads - L1 hit).
        int se[2], ge[2];
#pragma unroll
        for (int rg = 0; rg < 2; ++rg) {
            int e = ebase + rg * 16 + ln;
            int s = 0, g = 0;
            if (e < N_EDGES) {
                if (mode64) {
                    s = (int)((const long long*)eiv)[e];
                    g = (int)((const long long*)eiv)[N_EDGES + e];
                } else {
                    s = ((const int*)eiv)[e];
                    g = ((const int*)eiv)[N_EDGES + e];
                }
            }
            se[rg] = s; ge[rg] = g;
        }

        // Gather directly into A-fragment layout + fused bias+elu. Per rg: 8 loads
        // in flight, combined while the other rg's loads travel.
        f16x8 A[2][4];
#pragma unroll
        for (int rg = 0; rg < 2; ++rg) {
            const _Float16* pa = P + (size_t)se[rg] * 256 + kg * 8;
            const _Float16* pb = P + (size_t)ge[rg] * 256 + 128 + kg * 8;
            f16x8 Ga[4], Gb[4];
#pragma unroll
            for (int ks = 0; ks < 4; ++ks) {
                Ga[ks] = *(const f16x8*)(pa + ks * 32);
                Gb[ks] = *(const f16x8*)(pb + ks * 32);
            }
#pragma unroll
            for (int ks = 0; ks < 4; ++ks) {
                f16x8 s = Ga[ks] + Gb[ks] + b1f[ks];   // v_pk_add_f16
                f16x8 vh;
#pragma unroll
                for (int j = 0; j < 8; ++j)
                    vh[j] = (_Float16)elu_f((float)s[j]);
                A[rg][ks] = vh;
            }
        }

        // MFMA: 2 row-groups x 8 col-groups x 4 k-steps; B-frags from sW2T.
        f32x4 acc0[8], acc1[8];
#pragma unroll
        for (int cg = 0; cg < 8; ++cg) {
            acc0[cg] = (f32x4){0.f, 0.f, 0.f, 0.f};
            acc1[cg] = (f32x4){0.f, 0.f, 0.f, 0.f};
        }
#pragma unroll
        for (int ks = 0; ks < 4; ++ks) {
#pragma unroll
            for (int cg = 0; cg < 8; ++cg) {
                f16x8 bfr = *(const f16x8*)(&sW2T[(cg * 16 + ln) * LDH + ks * 32 + kg * 8]);
                acc0[cg] = __builtin_amdgcn_mfma_f32_16x16x32_f16(A[0][ks], bfr, acc0[cg], 0, 0, 0);
                acc1[cg] = __builtin_amdgcn_mfma_f32_16x16x32_f16(A[1][ks], bfr, acc1[cg], 0, 0, 0);
            }
        }

        // Layer 3 fused. D-layout: col=cg*16+ln, edge=rg*16+kg*4+reg. Reduce over ln.
#pragma unroll
        for (int rg = 0; rg < 2; ++rg) {
            float p[4] = {0.f, 0.f, 0.f, 0.f};
#pragma unroll
            for (int cg = 0; cg < 8; ++cg) {
#pragma unroll
                for (int reg = 0; reg < 4; ++reg) {
                    float h = (rg == 0 ? acc0[cg][reg] : acc1[cg][reg]) + b2v[cg];
                    p[reg] += elu_f(h) * w3v[cg];
                }
            }
#pragma unroll
            for (int m = 1; m < 16; m <<= 1)
#pragma unroll
                for (int reg = 0; reg < 4; ++reg) p[reg] += __shfl_xor(p[reg], m, 64);
            if (ln == 0) {
#pragma unroll
                for (int reg = 0; reg < 4; ++reg) {
                    int e = ebase + rg * 16 + kg * 4 + reg;
                    if (e < N_EDGES) out[e] = p[reg] + b3v;
                }
            }
        }
    }
}

extern "C" void kernel_launch(void* const* d_in, const int* in_sizes, int n_in,
                              void* d_out, int out_size, void* d_ws, size_t ws_size,
                              hipStream_t stream) {
    const float* x  = (const float*)d_in[0];
    const void*  ei = d_in[1];
    const float* W1 = (const float*)d_in[2];
    const float* b1 = (const float*)d_in[3];
    const float* W2 = (const float*)d_in[4];
    const float* b2 = (const float*)d_in[5];
    const float* W3 = (const float*)d_in[6];
    const float* b3 = (const float*)d_in[7];
    float* out = (float*)d_out;

    _Float16* P = (_Float16*)((char*)d_ws + 256);  // 100000*256 f16 = 51.2 MB

    k1_node_linear<<<1024, 256, 0, stream>>>(x, W1, P);
    k2_edge_mlp<<<1172, 256, 0, stream>>>(P, ei, b1, W2, b2, W3, b3, out);
}

// Round 8
// 212.111 us; speedup vs baseline: 2.3351x; 1.5480x over previous
//
#include <hip/hip_runtime.h>

#define N_NODES 100000
#define N_EDGES 600000
#define NT1 782     // k1 node tiles of 128
#define NT2 9375    // k2 edge tiles of 64 (600000 = 9375*64 exactly)
#define LDH 136     // padded row stride (f16 elems), 16B-aligned rows
#define G1H 512     // k1 blocks per half (grid = 1024)

typedef _Float16 f16x8 __attribute__((ext_vector_type(8)));
typedef __attribute__((ext_vector_type(4))) float f32x4;

__device__ __forceinline__ float elu_f(float v) {
    return v > 0.0f ? v : (__expf(v) - 1.0f);
}

// P[n][half*128 + j] = f16( x[n] @ W1[half*128 + k][j] ).  Single-pass f16 MFMA.
// (unchanged from R5 — proven)
extern "C" __global__ __launch_bounds__(256, 4)
void k1_node_linear(const float* __restrict__ x, const float* __restrict__ W1,
                    _Float16* __restrict__ P) {
    __shared__ __align__(16) _Float16 sX[128 * LDH];

    const int t = threadIdx.x;
    const int w = t >> 6, lane = t & 63;
    const int ln = lane & 15, kg = lane >> 4;
    const int kcf = t & 15;
    const int lef = t >> 4;
    const int half = (blockIdx.x >= G1H) ? 1 : 0;
    const int t0 = blockIdx.x - half * G1H;

    f16x8 bf[2][4];
#pragma unroll
    for (int c = 0; c < 2; ++c) {
        const int n = w * 32 + c * 16 + ln;
#pragma unroll
        for (int ks = 0; ks < 4; ++ks) {
            f16x8 v;
#pragma unroll
            for (int j = 0; j < 8; ++j) {
                int k = half * 128 + ks * 32 + kg * 8 + j;
                v[j] = (_Float16)W1[k * 128 + n];
            }
            bf[c][ks] = v;
        }
    }

    for (int tile = t0; tile < NT1; tile += G1H) {
        const int n0 = tile * 128;
        __syncthreads();
#pragma unroll 2
        for (int r = 0; r < 8; ++r) {
            int le = r * 16 + lef;
            int n = n0 + le;
            float4 a0 = make_float4(0.f, 0.f, 0.f, 0.f), a1 = a0;
            if (n < N_NODES) {
                const float* p = x + (size_t)n * 128 + kcf * 8;
                a0 = *(const float4*)p; a1 = *(const float4*)(p + 4);
            }
            float f[8] = {a0.x, a0.y, a0.z, a0.w, a1.x, a1.y, a1.z, a1.w};
            f16x8 vh;
#pragma unroll
            for (int j = 0; j < 8; ++j) vh[j] = (_Float16)f[j];
            *(f16x8*)(&sX[le * LDH + kcf * 8]) = vh;
        }
        __syncthreads();

        f32x4 acc[8][2];
#pragma unroll
        for (int rt = 0; rt < 8; ++rt)
#pragma unroll
            for (int c = 0; c < 2; ++c) acc[rt][c] = (f32x4){0.f, 0.f, 0.f, 0.f};

#pragma unroll
        for (int ks = 0; ks < 4; ++ks) {
#pragma unroll
            for (int rt = 0; rt < 8; ++rt) {
                f16x8 a = *(const f16x8*)(&sX[(rt * 16 + ln) * LDH + ks * 32 + kg * 8]);
#pragma unroll
                for (int c = 0; c < 2; ++c)
                    acc[rt][c] = __builtin_amdgcn_mfma_f32_16x16x32_f16(a, bf[c][ks], acc[rt][c], 0, 0, 0);
            }
        }

        __syncthreads();
#pragma unroll
        for (int rt = 0; rt < 8; ++rt)
#pragma unroll
            for (int c = 0; c < 2; ++c) {
                int col = w * 32 + c * 16 + ln;
#pragma unroll
                for (int reg = 0; reg < 4; ++reg) {
                    int row = rt * 16 + kg * 4 + reg;
                    sX[row * LDH + col] = (_Float16)acc[rt][c][reg];
                }
            }
        __syncthreads();
        {
            int row_l = t >> 1, seg = t & 1;
            int n = n0 + row_l;
            if (n < N_NODES) {
                _Float16* dst = P + (size_t)n * 256 + half * 128 + seg * 64;
                const _Float16* srcp = &sX[row_l * LDH + seg * 64];
#pragma unroll
                for (int i = 0; i < 8; ++i)
                    *(f16x8*)(dst + i * 8) = *(const f16x8*)(srcp + i * 8);
            }
        }
    }
}

// k2: 64-edge tiles, single-barrier software pipeline through double-buffered LDS.
// Held set across the compute phase: Ga[4]+Gb[4] (32 VGPR), consumed BEFORE the
// barrier (no cross-barrier register arrays — the R6/R7 spill trap).
extern "C" __global__ __launch_bounds__(256, 3)
void k2_edge_mlp(const _Float16* __restrict__ P, const void* __restrict__ eiv,
                 const float* __restrict__ b1, const float* __restrict__ W2,
                 const float* __restrict__ b2, const float* __restrict__ W3,
                 const float* __restrict__ b3, float* __restrict__ out) {
    __shared__ __align__(16) _Float16 sH[2][64 * LDH];   // 34.8 KB
    __shared__ float sPart[2][4][64];                    // 2 KB
    __shared__ int sFlag;

    const int t = threadIdx.x;
    const int w = t >> 6, lane = t & 63;
    const int ln = lane & 15, kg = lane >> 4;
    const int row = t >> 2;          // staging row 0..63
    const int kc0 = (t & 3) * 4;     // staging k-chunk base (of 16 chunks/row)
    const float b3v = b3[0];
    const int stride = gridDim.x;

    // int64-vs-int32 edge_index detection (wave 0).
    if (t < 64) {
        unsigned v = ((const unsigned*)eiv)[2 * t + 1];
        unsigned long long bm = __ballot(v == 0u);
        if (t == 0) sFlag = (bm == ~0ull) ? 1 : 0;
    }

    // b1 slice for this thread's 4 staged chunks (f16).
    f16x8 b1f[4];
#pragma unroll
    for (int i = 0; i < 4; ++i)
#pragma unroll
        for (int j = 0; j < 8; ++j) b1f[i][j] = (_Float16)b1[(kc0 + i) * 8 + j];

    float w3v[2], b2v[2];
#pragma unroll
    for (int c = 0; c < 2; ++c) {
        int col = w * 32 + c * 16 + ln;
        w3v[c] = W3[col]; b2v[c] = b2[col];
    }

    // W2 fragments (single f16) for this wave's 32-col strip (R5-proven, 32 VGPR).
    f16x8 bfw[2][4];
#pragma unroll
    for (int c = 0; c < 2; ++c) {
        const int n = w * 32 + c * 16 + ln;
#pragma unroll
        for (int ks = 0; ks < 4; ++ks) {
            f16x8 v;
#pragma unroll
            for (int j = 0; j < 8; ++j) {
                int k = ks * 32 + kg * 8 + j;
                v[j] = (_Float16)W2[k * 128 + n];
            }
            bfw[c][ks] = v;
        }
    }
    __syncthreads();   // sFlag ready
    const int mode64 = sFlag;

    const int tile0 = blockIdx.x;   // 768 <= NT2 always

    // --- Prologue: tile0 staged without overlap (one-time exposed latency). ---
    int se_nx, ge_nx;
    {
        int e = tile0 * 64 + row;
        if (mode64) {
            se_nx = (int)((const long long*)eiv)[e];
            ge_nx = (int)((const long long*)eiv)[N_EDGES + e];
        } else {
            se_nx = ((const int*)eiv)[e];
            ge_nx = ((const int*)eiv)[N_EDGES + e];
        }
    }
    {
        const _Float16* pa = P + (size_t)se_nx * 256 + kc0 * 8;
        const _Float16* pb = P + (size_t)ge_nx * 256 + 128 + kc0 * 8;
        f16x8 Ga[4], Gb[4];
#pragma unroll
        for (int i = 0; i < 4; ++i) {
            Ga[i] = *(const f16x8*)(pa + i * 8);
            Gb[i] = *(const f16x8*)(pb + i * 8);
        }
#pragma unroll
        for (int i = 0; i < 4; ++i) {
            f16x8 vh;
#pragma unroll
            for (int j = 0; j < 8; ++j)
                vh[j] = (_Float16)elu_f((float)Ga[i][j] + (float)Gb[i][j] + (float)b1f[i][j]);
            *(f16x8*)(&sH[0][row * LDH + (kc0 + i) * 8]) = vh;
        }
    }
    // Indices for tile1 (clamped; junk-safe).
    {
        int t1 = tile0 + stride;
        int t1c = (t1 < NT2) ? t1 : tile0;
        int e = t1c * 64 + row;
        if (mode64) {
            se_nx = (int)((const long long*)eiv)[e];
            ge_nx = (int)((const long long*)eiv)[N_EDGES + e];
        } else {
            se_nx = ((const int*)eiv)[e];
            ge_nx = ((const int*)eiv)[N_EDGES + e];
        }
    }
    __syncthreads();   // sH[0] ready

    int p = 0;
    int prevE0 = -1;
    for (int tile = tile0; tile < NT2; tile += stride) {
        const int nt = tile + stride;
        const int ntc = (nt < NT2) ? nt : tile;

        // (1) Issue gathers for tile nt (indices already in registers).
        const _Float16* pa = P + (size_t)se_nx * 256 + kc0 * 8;
        const _Float16* pb = P + (size_t)ge_nx * 256 + 128 + kc0 * 8;
        f16x8 Ga[4], Gb[4];
#pragma unroll
        for (int i = 0; i < 4; ++i) {
            Ga[i] = *(const f16x8*)(pa + i * 8);
            Gb[i] = *(const f16x8*)(pb + i * 8);
        }

        // (1b) Load indices for tile nt+stride (consumed next iteration).
        {
            int n2 = nt + stride;
            int n2c = (n2 < NT2) ? n2 : ntc;
            int e = n2c * 64 + row;
            if (mode64) {
                se_nx = (int)((const long long*)eiv)[e];
                ge_nx = (int)((const long long*)eiv)[N_EDGES + e];
            } else {
                se_nx = ((const int*)eiv)[e];
                ge_nx = ((const int*)eiv)[N_EDGES + e];
            }
        }

        // (2) Out-write for the previous tile from sPart[p^1].
        if (prevE0 >= 0 && t < 64)
            out[prevE0 + t] = sPart[p ^ 1][0][t] + sPart[p ^ 1][1][t] +
                              sPart[p ^ 1][2][t] + sPart[p ^ 1][3][t] + b3v;

        // (3) MFMA on sH[p] + fused layer 3 -> sPart[p].
        f32x4 acc[4][2];
#pragma unroll
        for (int rt = 0; rt < 4; ++rt)
#pragma unroll
            for (int c = 0; c < 2; ++c) acc[rt][c] = (f32x4){0.f, 0.f, 0.f, 0.f};

#pragma unroll
        for (int ks = 0; ks < 4; ++ks) {
#pragma unroll
            for (int rt = 0; rt < 4; ++rt) {
                f16x8 a = *(const f16x8*)(&sH[p][(rt * 16 + ln) * LDH + ks * 32 + kg * 8]);
#pragma unroll
                for (int c = 0; c < 2; ++c)
                    acc[rt][c] = __builtin_amdgcn_mfma_f32_16x16x32_f16(a, bfw[c][ks], acc[rt][c], 0, 0, 0);
            }
        }

#pragma unroll
        for (int rt = 0; rt < 4; ++rt) {
            float pr[4] = {0.f, 0.f, 0.f, 0.f};
#pragma unroll
            for (int c = 0; c < 2; ++c) {
#pragma unroll
                for (int reg = 0; reg < 4; ++reg)
                    pr[reg] += elu_f(acc[rt][c][reg] + b2v[c]) * w3v[c];
            }
#pragma unroll
            for (int m = 1; m < 16; m <<= 1)
#pragma unroll
                for (int reg = 0; reg < 4; ++reg) pr[reg] += __shfl_xor(pr[reg], m, 64);
            if (ln == 0) {
#pragma unroll
                for (int reg = 0; reg < 4; ++reg)
                    sPart[p][w][rt * 16 + kg * 4 + reg] = pr[reg];
            }
        }

        // (4) Combine gathered tile nt -> sH[p^1] (vmcnt wait lands here).
#pragma unroll
        for (int i = 0; i < 4; ++i) {
            f16x8 vh;
#pragma unroll
            for (int j = 0; j < 8; ++j)
                vh[j] = (_Float16)elu_f((float)Ga[i][j] + (float)Gb[i][j] + (float)b1f[i][j]);
            *(f16x8*)(&sH[p ^ 1][row * LDH + (kc0 + i) * 8]) = vh;
        }

        prevE0 = tile * 64;
        __syncthreads();   // the ONLY per-tile barrier
        p ^= 1;
    }

    // Epilogue: out-write for the last tile.
    if (prevE0 >= 0 && t < 64)
        out[prevE0 + t] = sPart[p ^ 1][0][t] + sPart[p ^ 1][1][t] +
                          sPart[p ^ 1][2][t] + sPart[p ^ 1][3][t] + b3v;
}

extern "C" void kernel_launch(void* const* d_in, const int* in_sizes, int n_in,
                              void* d_out, int out_size, void* d_ws, size_t ws_size,
                              hipStream_t stream) {
    const float* x  = (const float*)d_in[0];
    const void*  ei = d_in[1];
    const float* W1 = (const float*)d_in[2];
    const float* b1 = (const float*)d_in[3];
    const float* W2 = (const float*)d_in[4];
    const float* b2 = (const float*)d_in[5];
    const float* W3 = (const float*)d_in[6];
    const float* b3 = (const float*)d_in[7];
    float* out = (float*)d_out;

    _Float16* P = (_Float16*)((char*)d_ws + 256);  // 100000*256 f16 = 51.2 MB

    k1_node_linear<<<1024, 256, 0, stream>>>(x, W1, P);
    k2_edge_mlp<<<768, 256, 0, stream>>>(P, ei, b1, W2, b2, W3, b3, out);
}